// Round 3
// baseline (131353.137 us; speedup 1.0000x reference)
//
#include <hip/hip_runtime.h>
#include <cstdint>

#define T_STEPS 131072
#define FEATS 128
#define HID 64
#define LAT 16
#define GATES 256  // 4*HID

typedef float v4f __attribute__((ext_vector_type(4)));

#define LOG2E 1.44269504088896340736f

// ---------- math helpers ----------
__device__ __forceinline__ float frcp(float x) { return __builtin_amdgcn_rcpf(x); }
__device__ __forceinline__ float fexp2(float x) { return __builtin_amdgcn_exp2f(x); }

__device__ __forceinline__ float sigm_f(float x) {
  float e = fexp2(-LOG2E * fabsf(x));
  float r = frcp(1.0f + e);
  return x >= 0.0f ? r : e * r;
}
__device__ __forceinline__ float tanh_f(float x) {
  float e = fexp2(-2.0f * LOG2E * fabsf(x));
  float r = (1.0f - e) * frcp(1.0f + e);
  return copysignf(r, x);
}
__device__ __forceinline__ float prelu(float x, float a) { return x > 0.0f ? x : a * x; }

// =====================================================================
// Kernel A: xg4[t][e] = float4(gate0..3 of element e) where
// gate_g[e] = b[g*64+e] + x_t . W_ih[g*64+e, :].  Layout [t][e][4] so kB's
// lane e reads one coalesced float4 per step.
// Each block owns one j-half (128 rows) with W^T staged in LDS (64KB).
// =====================================================================
__global__ __launch_bounds__(256) void kA(const float* __restrict__ x,
                                          const float* __restrict__ W_ih,
                                          const float* __restrict__ b_ih,
                                          const float* __restrict__ b_hh,
                                          float* __restrict__ xg,
                                          int t0, int n) {
  __shared__ float wt[FEATS * 128];                 // [k][jj] transposed half
  __shared__ __align__(16) float xb[4][FEATS];      // per-wave x row
  const int tid = threadIdx.x;
  const int w = tid >> 6, l = tid & 63;
  const int half = blockIdx.x & 1;
  const int pair = blockIdx.x >> 1;                 // 0..255

  for (int idx = tid; idx < 128 * FEATS; idx += 256) {
    int jj = idx >> 7, k = idx & 127;
    wt[k * 128 + jj] = W_ih[(size_t)(half * 128 + jj) * FEATS + k];
  }
  const int j0 = half * 128 + 2 * l;                // even row; j0+1 same gate blk
  const float b0 = b_ih[j0] + b_hh[j0];
  const float b1 = b_ih[j0 + 1] + b_hh[j0 + 1];
  const int g0 = j0 >> 6;                           // gate index 0..3
  const int e0 = j0 & 63;                           // element index (even)
  __syncthreads();

  for (int s = pair * 4 + w; s < n; s += 1024) {
    const size_t t = (size_t)(t0 + s);
    *(float2*)&xb[w][2 * l] = *(const float2*)&x[t * FEATS + 2 * l];
    float a0 = b0, a0b = 0.f, a1 = b1, a1b = 0.f;
#pragma unroll
    for (int k = 0; k < FEATS; k += 4) {
      float4 xk = *(const float4*)&xb[w][k];
      float2 w0 = *(const float2*)&wt[(k + 0) * 128 + 2 * l];
      float2 w1 = *(const float2*)&wt[(k + 1) * 128 + 2 * l];
      float2 w2 = *(const float2*)&wt[(k + 2) * 128 + 2 * l];
      float2 w3 = *(const float2*)&wt[(k + 3) * 128 + 2 * l];
      a0  += xk.x * w0.x; a0b += xk.y * w1.x;
      a0  += xk.z * w2.x; a0b += xk.w * w3.x;
      a1  += xk.x * w0.y; a1b += xk.y * w1.y;
      a1  += xk.z * w2.y; a1b += xk.w * w3.y;
    }
    float* dst = &xg[(size_t)s * GATES];
    dst[e0 * 4 + g0]       = a0 + a0b;
    dst[(e0 + 1) * 4 + g0] = a1 + a1b;
  }
}

// =====================================================================
// Kernel B: sequential LSTM recurrence. ONE wave (64 lanes). Lane e owns
// element e: all 4 gate rows of W_hh in 256 VGPRs, c in a register, gates
// fully lane-local (no shuffles, no barriers). h broadcast = 16 uniform
// ds_read_b128 per step; h update = 1 ds_write_b32. Per-wave LDS ordering
// makes the write->read sequence safe without sync.
// =====================================================================
__global__ __launch_bounds__(64, 1) void kB(const float4* __restrict__ xg4,
                                            const float* __restrict__ W_hh,
                                            const float* __restrict__ h0,
                                            const float* __restrict__ c0,
                                            float* __restrict__ state,
                                            float* __restrict__ h2out,
                                            int t0, int nsteps, int first) {
  __shared__ __align__(16) float hbuf[HID];
  const int e = threadIdx.x;                 // 0..63

  // 4 gate rows for element e: j = g*64 + e
  v4f wi[16], wf[16], wg[16], wo[16];
#pragma unroll
  for (int k = 0; k < 16; ++k) {
    wi[k] = *(const v4f*)&W_hh[(size_t)(0 * HID + e) * HID + 4 * k];
    wf[k] = *(const v4f*)&W_hh[(size_t)(1 * HID + e) * HID + 4 * k];
    wg[k] = *(const v4f*)&W_hh[(size_t)(2 * HID + e) * HID + 4 * k];
    wo[k] = *(const v4f*)&W_hh[(size_t)(3 * HID + e) * HID + 4 * k];
  }

  hbuf[e] = first ? h0[e] : state[e];
  float c_reg = first ? c0[e] : state[HID + e];
  float hlast = 0.0f;

  float4 x0 = xg4[(size_t)0 * HID + e];
  float4 x1 = xg4[(size_t)1 * HID + e];
  float4 x2 = xg4[(size_t)2 * HID + e];
  float4 x3 = xg4[(size_t)3 * HID + e];

#define LSTM_STEP(XV, S)                                                   \
  {                                                                        \
    const v4f* hb = (const v4f*)hbuf;                                      \
    v4f ai = {(XV).x, 0.f, 0.f, 0.f};                                      \
    v4f af = {(XV).y, 0.f, 0.f, 0.f};                                      \
    v4f ag = {(XV).z, 0.f, 0.f, 0.f};                                      \
    v4f ao = {(XV).w, 0.f, 0.f, 0.f};                                      \
    _Pragma("unroll")                                                      \
    for (int kk = 0; kk < 16; ++kk) {                                      \
      v4f h4 = hb[kk];                                                     \
      ai = __builtin_elementwise_fma(h4, wi[kk], ai);                      \
      af = __builtin_elementwise_fma(h4, wf[kk], af);                      \
      ag = __builtin_elementwise_fma(h4, wg[kk], ag);                      \
      ao = __builtin_elementwise_fma(h4, wo[kk], ao);                      \
    }                                                                      \
    float gi = (ai.x + ai.y) + (ai.z + ai.w);                              \
    float gf = (af.x + af.y) + (af.z + af.w);                              \
    float gg = (ag.x + ag.y) + (ag.z + ag.w);                              \
    float go = (ao.x + ao.y) + (ao.z + ao.w);                              \
    float iv = sigm_f(gi);                                                 \
    float fv = sigm_f(gf);                                                 \
    float ov = sigm_f(go);                                                 \
    float tg = tanh_f(gg);                                                 \
    float c2 = fv * c_reg + iv * tg;                                       \
    float h2v = ov * tanh_f(c2);                                           \
    c_reg = c2;                                                            \
    hlast = h2v;                                                           \
    hbuf[e] = h2v;                                                         \
    h2out[(size_t)(t0 + (S)) * 128 + e] = h2v;                             \
  }

  for (int s = 0; s < nsteps; s += 4) {
    { float4 nx = xg4[(size_t)(s + 4) * HID + e]; LSTM_STEP(x0, s + 0); x0 = nx; }
    { float4 nx = xg4[(size_t)(s + 5) * HID + e]; LSTM_STEP(x1, s + 1); x1 = nx; }
    { float4 nx = xg4[(size_t)(s + 6) * HID + e]; LSTM_STEP(x2, s + 2); x2 = nx; }
    { float4 nx = xg4[(size_t)(s + 7) * HID + e]; LSTM_STEP(x3, s + 3); x3 = nx; }
  }
  state[e] = hlast;
  state[HID + e] = c_reg;
#undef LSTM_STEP
}

// =====================================================================
// Kernel C: VAE encoder/decoder, fully parallel over t. One wave per t,
// 8 waves/block, all weights transposed in LDS (~98KB), ping-pong act bufs.
// h2 arrives in out[t*128+0..63]; row is overwritten by the same wave at
// the end of the iteration.
// =====================================================================
__device__ __forceinline__ void stageT(float* dst, const float* __restrict__ src,
                                       int rows, int colsShift, int tid, int nthr) {
  const int total = rows << colsShift;
  const int cmask = (1 << colsShift) - 1;
  for (int idx = tid; idx < total; idx += nthr) {
    int jr = idx >> colsShift, k = idx & cmask;
    dst[k * rows + jr] = src[idx];
  }
}

__global__ __launch_bounds__(512) void kC(const float* __restrict__ eps,
                                          const int* __restrict__ trainp,
                                          const float* __restrict__ We1, const float* __restrict__ be1, const float* __restrict__ ae1,
                                          const float* __restrict__ We2, const float* __restrict__ be2, const float* __restrict__ ae2,
                                          const float* __restrict__ We3, const float* __restrict__ be3,
                                          const float* __restrict__ Wd1, const float* __restrict__ bd1, const float* __restrict__ ad1,
                                          const float* __restrict__ Wd2, const float* __restrict__ bd2, const float* __restrict__ ad2,
                                          const float* __restrict__ Wd3, const float* __restrict__ bd3,
                                          float* __restrict__ out) {
  __shared__ float wt1[4096], wt2[4096], wt3[2048], wtd1[1024], wtd2[4096], wtd3[8192];
  __shared__ float bb[416];
  __shared__ __align__(16) float abuf[8][2][HID];
  const int tid = threadIdx.x;

  stageT(wt1, We1, 64, 6, tid, 512);
  stageT(wt2, We2, 64, 6, tid, 512);
  stageT(wt3, We3, 32, 6, tid, 512);
  stageT(wtd1, Wd1, 64, 4, tid, 512);
  stageT(wtd2, Wd2, 64, 6, tid, 512);
  stageT(wtd3, Wd3, 128, 6, tid, 512);
  for (int i = tid; i < 416; i += 512) {
    float v;
    if (i < 64)       v = be1[i];
    else if (i < 128) v = be2[i - 64];
    else if (i < 160) v = be3[i - 128];
    else if (i < 224) v = bd1[i - 160];
    else if (i < 288) v = bd2[i - 224];
    else              v = bd3[i - 288];
    bb[i] = v;
  }
  const float a1 = *ae1, a2 = *ae2, ad1v = *ad1, ad2v = *ad2;
  const int train = *trainp;
  __syncthreads();

  const int w = tid >> 6, l = tid & 63, le = l & 15;
  float* bufA = abuf[w][0];
  float* bufB = abuf[w][1];

  for (int it = 0; it < 64; ++it) {
    const size_t t = ((size_t)blockIdx.x << 9) + (size_t)(it << 3) + (size_t)w;
    bufA[l] = out[t * 128 + l];  // h2 row (written by kB)
    // e1 = prelu(We1 . h2 + be1): bufA -> bufB
    {
      float accA = bb[l], accB = 0.f;
#pragma unroll
      for (int k = 0; k < 64; k += 4) {
        float4 v = *(const float4*)&bufA[k];
        accA += v.x * wt1[(k + 0) * 64 + l];
        accB += v.y * wt1[(k + 1) * 64 + l];
        accA += v.z * wt1[(k + 2) * 64 + l];
        accB += v.w * wt1[(k + 3) * 64 + l];
      }
      bufB[l] = prelu(accA + accB, a1);
    }
    // e2: bufB -> bufA
    {
      float accA = bb[64 + l], accB = 0.f;
#pragma unroll
      for (int k = 0; k < 64; k += 4) {
        float4 v = *(const float4*)&bufB[k];
        accA += v.x * wt2[(k + 0) * 64 + l];
        accB += v.y * wt2[(k + 1) * 64 + l];
        accA += v.z * wt2[(k + 2) * 64 + l];
        accB += v.w * wt2[(k + 3) * 64 + l];
      }
      bufA[l] = prelu(accA + accB, a2);
    }
    // ml = We3 . e2 + be3 (32 outputs in lanes 0..31)
    float m;
    {
      const int jj = l & 31;
      float accA = bb[128 + jj], accB = 0.f;
#pragma unroll
      for (int k = 0; k < 64; k += 4) {
        float4 v = *(const float4*)&bufA[k];
        accA += v.x * wt3[(k + 0) * 32 + jj];
        accB += v.y * wt3[(k + 1) * 32 + jj];
        accA += v.z * wt3[(k + 2) * 32 + jj];
        accB += v.w * wt3[(k + 3) * 32 + jj];
      }
      m = accA + accB;
    }
    if (l < 16)      out[(size_t)T_STEPS * 128 + t * LAT + l] = m;          // mu
    else if (l < 32) out[(size_t)T_STEPS * 144 + t * LAT + (l - 16)] = m;   // lv
    float muv = __shfl(m, le);
    float lvv = __shfl(m, 16 + le);
    float ev = eps[t * LAT + le];
    float z = train ? (muv + ev * fexp2(0.5f * LOG2E * lvv)) : muv;
    if (l < 16) bufB[l] = z;
    // d1 = prelu(Wd1 . z + bd1): bufB(16) -> bufA
    {
      float accA = bb[160 + l], accB = 0.f;
#pragma unroll
      for (int k = 0; k < 16; k += 4) {
        float4 v = *(const float4*)&bufB[k];
        accA += v.x * wtd1[(k + 0) * 64 + l];
        accB += v.y * wtd1[(k + 1) * 64 + l];
        accA += v.z * wtd1[(k + 2) * 64 + l];
        accB += v.w * wtd1[(k + 3) * 64 + l];
      }
      bufA[l] = prelu(accA + accB, ad1v);
    }
    // d2: bufA -> bufB
    {
      float accA = bb[224 + l], accB = 0.f;
#pragma unroll
      for (int k = 0; k < 64; k += 4) {
        float4 v = *(const float4*)&bufA[k];
        accA += v.x * wtd2[(k + 0) * 64 + l];
        accB += v.y * wtd2[(k + 1) * 64 + l];
        accA += v.z * wtd2[(k + 2) * 64 + l];
        accB += v.w * wtd2[(k + 3) * 64 + l];
      }
      bufB[l] = prelu(accA + accB, ad2v);
    }
    // out = 4*tanh(Wd3 . d2 + bd3): lane l -> outputs 2l, 2l+1
    {
      float acc0 = bb[288 + 2 * l], acc0b = 0.f;
      float acc1 = bb[288 + 2 * l + 1], acc1b = 0.f;
#pragma unroll
      for (int k = 0; k < 64; k += 2) {
        float2 v = *(const float2*)&bufB[k];
        float2 w0 = *(const float2*)&wtd3[(k + 0) * 128 + 2 * l];
        float2 w1 = *(const float2*)&wtd3[(k + 1) * 128 + 2 * l];
        acc0  += v.x * w0.x; acc0b += v.y * w1.x;
        acc1  += v.x * w0.y; acc1b += v.y * w1.y;
      }
      float o0 = 4.0f * tanh_f(acc0 + acc0b);
      float o1 = 4.0f * tanh_f(acc1 + acc1b);
      *(float2*)&out[t * 128 + 2 * l] = make_float2(o0, o1);
    }
  }
}

// =====================================================================
extern "C" void kernel_launch(void* const* d_in, const int* in_sizes, int n_in,
                              void* d_out, int out_size, void* d_ws, size_t ws_size,
                              hipStream_t stream) {
  (void)in_sizes; (void)n_in; (void)out_size;
  const float* x    = (const float*)d_in[0];
  const float* eps  = (const float*)d_in[1];
  const float* h0   = (const float*)d_in[2];
  const float* c0   = (const float*)d_in[3];
  const int*   tr   = (const int*)d_in[4];
  const float* W_ih = (const float*)d_in[5];
  const float* W_hh = (const float*)d_in[6];
  const float* b_ih = (const float*)d_in[7];
  const float* b_hh = (const float*)d_in[8];
  const float* We1  = (const float*)d_in[9];
  const float* be1  = (const float*)d_in[10];
  const float* ae1  = (const float*)d_in[11];
  const float* We2  = (const float*)d_in[12];
  const float* be2  = (const float*)d_in[13];
  const float* ae2  = (const float*)d_in[14];
  const float* We3  = (const float*)d_in[15];
  const float* be3  = (const float*)d_in[16];
  const float* Wd1  = (const float*)d_in[17];
  const float* bd1  = (const float*)d_in[18];
  const float* ad1  = (const float*)d_in[19];
  const float* Wd2  = (const float*)d_in[20];
  const float* bd2  = (const float*)d_in[21];
  const float* ad2  = (const float*)d_in[22];
  const float* Wd3  = (const float*)d_in[23];
  const float* bd3  = (const float*)d_in[24];
  float* out = (float*)d_out;

  // ws layout: [state: 1024B][xg: (ch+8)*1024B]
  char* ws = (char*)d_ws;
  float* state = (float*)ws;
  float* xg    = (float*)(ws + 1024);

  long fit = (ws_size > 2048) ? (long)((ws_size - 1024) / (GATES * sizeof(float))) - 8 : 0;
  long ch = (fit < (long)T_STEPS) ? fit : (long)T_STEPS;
  ch &= ~3L;
  if (ch < 1024) ch = 1024;  // bounds graph at <=129 chunk pairs

  for (long t0 = 0; t0 < T_STEPS; t0 += ch) {
    int n = (int)(((long)T_STEPS - t0 < ch) ? ((long)T_STEPS - t0) : ch);
    hipLaunchKernelGGL(kA, dim3(512), dim3(256), 0, stream,
                       x, W_ih, b_ih, b_hh, xg, (int)t0, n);
    hipLaunchKernelGGL(kB, dim3(1), dim3(64), 0, stream,
                       (const float4*)xg, W_hh, h0, c0, state, out, (int)t0, n,
                       (t0 == 0) ? 1 : 0);
  }
  hipLaunchKernelGGL(kC, dim3(256), dim3(512), 0, stream,
                     eps, tr, We1, be1, ae1, We2, be2, ae2, We3, be3,
                     Wd1, bd1, ad1, Wd2, bd2, ad2, Wd3, bd3, out);
}

// Round 5
// 69316.913 us; speedup vs baseline: 1.8950x; 1.8950x over previous
//
#include <hip/hip_runtime.h>
#include <cstdint>

#define T_STEPS 131072
#define FEATS 128
#define HID 64
#define LAT 16
#define GATES 256  // 4*HID

typedef float v4f __attribute__((ext_vector_type(4)));
typedef _Float16 half_t;
typedef _Float16 half2_t __attribute__((ext_vector_type(2)));
typedef _Float16 v8h __attribute__((ext_vector_type(8)));

#define LOG2E 1.44269504088896340736f

// ---------- math helpers ----------
__device__ __forceinline__ float frcp(float x) { return __builtin_amdgcn_rcpf(x); }
__device__ __forceinline__ float fexp2(float x) { return __builtin_amdgcn_exp2f(x); }

__device__ __forceinline__ float sigm_f(float x) {
  float e = fexp2(-LOG2E * fabsf(x));
  float r = frcp(1.0f + e);
  return x >= 0.0f ? r : e * r;
}
__device__ __forceinline__ float tanh_f(float x) {
  float e = fexp2(-2.0f * LOG2E * fabsf(x));
  float r = (1.0f - e) * frcp(1.0f + e);
  return copysignf(r, x);
}
__device__ __forceinline__ float prelu(float x, float a) { return x > 0.0f ? x : a * x; }

__device__ __forceinline__ float fdot2(half2_t a, half2_t b, float c) {
#if __has_builtin(__builtin_amdgcn_fdot2)
  return __builtin_amdgcn_fdot2(a, b, c, false);
#else
  return c + (float)a.x * (float)b.x + (float)a.y * (float)b.y;
#endif
}

// =====================================================================
// Kernel A: xg4[t][e] = float4(gate0..3 of element e) where
// gate_g[e] = b[g*64+e] + x_t . W_ih[g*64+e, :].  Layout [t][e][4] so kB's
// lane e reads one coalesced float4 per step.
// =====================================================================
__global__ __launch_bounds__(256) void kA(const float* __restrict__ x,
                                          const float* __restrict__ W_ih,
                                          const float* __restrict__ b_ih,
                                          const float* __restrict__ b_hh,
                                          float* __restrict__ xg,
                                          int t0, int n) {
  __shared__ float wt[FEATS * 128];                 // [k][jj] transposed half
  __shared__ __align__(16) float xb[4][FEATS];      // per-wave x row
  const int tid = threadIdx.x;
  const int w = tid >> 6, l = tid & 63;
  const int half = blockIdx.x & 1;
  const int pair = blockIdx.x >> 1;                 // 0..255

  for (int idx = tid; idx < 128 * FEATS; idx += 256) {
    int jj = idx >> 7, k = idx & 127;
    wt[k * 128 + jj] = W_ih[(size_t)(half * 128 + jj) * FEATS + k];
  }
  const int j0 = half * 128 + 2 * l;                // even row; j0+1 same gate blk
  const float b0 = b_ih[j0] + b_hh[j0];
  const float b1 = b_ih[j0 + 1] + b_hh[j0 + 1];
  const int g0 = j0 >> 6;                           // gate index 0..3
  const int e0 = j0 & 63;                           // element index (even)
  __syncthreads();

  for (int s = pair * 4 + w; s < n; s += 1024) {
    const size_t t = (size_t)(t0 + s);
    *(float2*)&xb[w][2 * l] = *(const float2*)&x[t * FEATS + 2 * l];
    float a0 = b0, a0b = 0.f, a1 = b1, a1b = 0.f;
#pragma unroll
    for (int k = 0; k < FEATS; k += 4) {
      float4 xk = *(const float4*)&xb[w][k];
      float2 w0 = *(const float2*)&wt[(k + 0) * 128 + 2 * l];
      float2 w1 = *(const float2*)&wt[(k + 1) * 128 + 2 * l];
      float2 w2 = *(const float2*)&wt[(k + 2) * 128 + 2 * l];
      float2 w3 = *(const float2*)&wt[(k + 3) * 128 + 2 * l];
      a0  += xk.x * w0.x; a0b += xk.y * w1.x;
      a0  += xk.z * w2.x; a0b += xk.w * w3.x;
      a1  += xk.x * w0.y; a1b += xk.y * w1.y;
      a1  += xk.z * w2.y; a1b += xk.w * w3.y;
    }
    float* dst = &xg[(size_t)s * GATES];
    dst[e0 * 4 + g0]       = a0 + a0b;
    dst[(e0 + 1) * 4 + g0] = a1 + a1b;
  }
}

// =====================================================================
// Kernel B: sequential LSTM recurrence. ONE wave (64 lanes). Lane e owns
// element e: all 4 gate rows of W_hh as packed f16 pairs in 128 VGPRs
// (v_dot2_f32_f16: 2 MAC/instr). h lives in LDS as packed f16 (128B):
// 8 uniform ds_read_b128 per step, 1 ds_write_b16 update. Gates fully
// lane-local (no shuffles, no barriers). Per-wave in-order LDS pipe makes
// the write->read sequence safe without sync (validated rounds 2-3).
// =====================================================================
union HU {
  v8h v;
  half2_t h2[4];
};

__global__ __launch_bounds__(64, 1) void kB(const float4* __restrict__ xg4,
                                            const float* __restrict__ W_hh,
                                            const float* __restrict__ h0,
                                            const float* __restrict__ c0,
                                            float* __restrict__ state,
                                            float* __restrict__ h2out,
                                            int t0, int nsteps, int first) {
  __shared__ __align__(16) half_t hbuf[HID];
  const int e = threadIdx.x;                 // 0..63

  // 4 gate rows for element e (j = g*64+e), packed to f16 pairs.
  half2_t wi[32], wf[32], wg[32], wo[32];
#pragma unroll
  for (int k = 0; k < 32; ++k) {
    float2 a = *(const float2*)&W_hh[(size_t)(0 * HID + e) * HID + 2 * k];
    float2 b = *(const float2*)&W_hh[(size_t)(1 * HID + e) * HID + 2 * k];
    float2 c = *(const float2*)&W_hh[(size_t)(2 * HID + e) * HID + 2 * k];
    float2 d = *(const float2*)&W_hh[(size_t)(3 * HID + e) * HID + 2 * k];
    wi[k] = half2_t{(half_t)a.x, (half_t)a.y};
    wf[k] = half2_t{(half_t)b.x, (half_t)b.y};
    wg[k] = half2_t{(half_t)c.x, (half_t)c.y};
    wo[k] = half2_t{(half_t)d.x, (half_t)d.y};
  }

  float hinit = first ? h0[e] : state[e];
  hbuf[e] = (half_t)hinit;
  float c_reg = first ? c0[e] : state[HID + e];
  float hlast = hinit;

  float4 x0 = xg4[(size_t)0 * HID + e];
  float4 x1 = xg4[(size_t)1 * HID + e];
  float4 x2 = xg4[(size_t)2 * HID + e];
  float4 x3 = xg4[(size_t)3 * HID + e];

#define LSTM_STEP(XV, S)                                                   \
  {                                                                        \
    HU hu[8];                                                              \
    _Pragma("unroll")                                                      \
    for (int q = 0; q < 8; ++q) hu[q].v = ((const v8h*)hbuf)[q];           \
    float ag = (XV).z, af = (XV).y, ao = (XV).w, ai = (XV).x;              \
    _Pragma("unroll")                                                      \
    for (int p = 0; p < 32; ++p) {                                         \
      half2_t hp = hu[p >> 2].h2[p & 3];                                   \
      ag = fdot2(hp, wg[p], ag);                                           \
      af = fdot2(hp, wf[p], af);                                           \
      ao = fdot2(hp, wo[p], ao);                                           \
      ai = fdot2(hp, wi[p], ai);                                           \
    }                                                                      \
    float tg = tanh_f(ag);                                                 \
    float fv = sigm_f(af);                                                 \
    float iv = sigm_f(ai);                                                 \
    float ov = sigm_f(ao);                                                 \
    float c2 = fv * c_reg + iv * tg;                                       \
    float h2v = ov * tanh_f(c2);                                           \
    c_reg = c2;                                                            \
    hlast = h2v;                                                           \
    hbuf[e] = (half_t)h2v;                                                 \
    h2out[(size_t)(t0 + (S)) * 128 + e] = h2v;                             \
  }

  for (int s = 0; s < nsteps; s += 4) {
    { float4 nx = xg4[(size_t)(s + 4) * HID + e]; LSTM_STEP(x0, s + 0); x0 = nx; }
    { float4 nx = xg4[(size_t)(s + 5) * HID + e]; LSTM_STEP(x1, s + 1); x1 = nx; }
    { float4 nx = xg4[(size_t)(s + 6) * HID + e]; LSTM_STEP(x2, s + 2); x2 = nx; }
    { float4 nx = xg4[(size_t)(s + 7) * HID + e]; LSTM_STEP(x3, s + 3); x3 = nx; }
  }
  state[e] = hlast;
  state[HID + e] = c_reg;
#undef LSTM_STEP
}

// =====================================================================
// Kernel C: VAE encoder/decoder, fully parallel over t. One wave per t,
// 8 waves/block, all weights transposed in LDS (~98KB), ping-pong act bufs.
// h2 arrives in out[t*128+0..63]; row is overwritten by the same wave at
// the end of the iteration.
// =====================================================================
__device__ __forceinline__ void stageT(float* dst, const float* __restrict__ src,
                                       int rows, int colsShift, int tid, int nthr) {
  const int total = rows << colsShift;
  const int cmask = (1 << colsShift) - 1;
  for (int idx = tid; idx < total; idx += nthr) {
    int jr = idx >> colsShift, k = idx & cmask;
    dst[k * rows + jr] = src[idx];
  }
}

__global__ __launch_bounds__(512) void kC(const float* __restrict__ eps,
                                          const int* __restrict__ trainp,
                                          const float* __restrict__ We1, const float* __restrict__ be1, const float* __restrict__ ae1,
                                          const float* __restrict__ We2, const float* __restrict__ be2, const float* __restrict__ ae2,
                                          const float* __restrict__ We3, const float* __restrict__ be3,
                                          const float* __restrict__ Wd1, const float* __restrict__ bd1, const float* __restrict__ ad1,
                                          const float* __restrict__ Wd2, const float* __restrict__ bd2, const float* __restrict__ ad2,
                                          const float* __restrict__ Wd3, const float* __restrict__ bd3,
                                          float* __restrict__ out) {
  __shared__ float wt1[4096], wt2[4096], wt3[2048], wtd1[1024], wtd2[4096], wtd3[8192];
  __shared__ float bb[416];
  __shared__ __align__(16) float abuf[8][2][HID];
  const int tid = threadIdx.x;

  stageT(wt1, We1, 64, 6, tid, 512);
  stageT(wt2, We2, 64, 6, tid, 512);
  stageT(wt3, We3, 32, 6, tid, 512);
  stageT(wtd1, Wd1, 64, 4, tid, 512);
  stageT(wtd2, Wd2, 64, 6, tid, 512);
  stageT(wtd3, Wd3, 128, 6, tid, 512);
  for (int i = tid; i < 416; i += 512) {
    float v;
    if (i < 64)       v = be1[i];
    else if (i < 128) v = be2[i - 64];
    else if (i < 160) v = be3[i - 128];
    else if (i < 224) v = bd1[i - 160];
    else if (i < 288) v = bd2[i - 224];
    else              v = bd3[i - 288];
    bb[i] = v;
  }
  const float a1 = *ae1, a2 = *ae2, ad1v = *ad1, ad2v = *ad2;
  const int train = *trainp;
  __syncthreads();

  const int w = tid >> 6, l = tid & 63, le = l & 15;
  float* bufA = abuf[w][0];
  float* bufB = abuf[w][1];

  for (int it = 0; it < 64; ++it) {
    const size_t t = ((size_t)blockIdx.x << 9) + (size_t)(it << 3) + (size_t)w;
    bufA[l] = out[t * 128 + l];  // h2 row (written by kB)
    // e1 = prelu(We1 . h2 + be1): bufA -> bufB
    {
      float accA = bb[l], accB = 0.f;
#pragma unroll
      for (int k = 0; k < 64; k += 4) {
        float4 v = *(const float4*)&bufA[k];
        accA += v.x * wt1[(k + 0) * 64 + l];
        accB += v.y * wt1[(k + 1) * 64 + l];
        accA += v.z * wt1[(k + 2) * 64 + l];
        accB += v.w * wt1[(k + 3) * 64 + l];
      }
      bufB[l] = prelu(accA + accB, a1);
    }
    // e2: bufB -> bufA
    {
      float accA = bb[64 + l], accB = 0.f;
#pragma unroll
      for (int k = 0; k < 64; k += 4) {
        float4 v = *(const float4*)&bufB[k];
        accA += v.x * wt2[(k + 0) * 64 + l];
        accB += v.y * wt2[(k + 1) * 64 + l];
        accA += v.z * wt2[(k + 2) * 64 + l];
        accB += v.w * wt2[(k + 3) * 64 + l];
      }
      bufA[l] = prelu(accA + accB, a2);
    }
    // ml = We3 . e2 + be3 (32 outputs in lanes 0..31)
    float m;
    {
      const int jj = l & 31;
      float accA = bb[128 + jj], accB = 0.f;
#pragma unroll
      for (int k = 0; k < 64; k += 4) {
        float4 v = *(const float4*)&bufA[k];
        accA += v.x * wt3[(k + 0) * 32 + jj];
        accB += v.y * wt3[(k + 1) * 32 + jj];
        accA += v.z * wt3[(k + 2) * 32 + jj];
        accB += v.w * wt3[(k + 3) * 32 + jj];
      }
      m = accA + accB;
    }
    if (l < 16)      out[(size_t)T_STEPS * 128 + t * LAT + l] = m;          // mu
    else if (l < 32) out[(size_t)T_STEPS * 144 + t * LAT + (l - 16)] = m;   // lv
    float muv = __shfl(m, le);
    float lvv = __shfl(m, 16 + le);
    float ev = eps[t * LAT + le];
    float z = train ? (muv + ev * fexp2(0.5f * LOG2E * lvv)) : muv;
    if (l < 16) bufB[l] = z;
    // d1 = prelu(Wd1 . z + bd1): bufB(16) -> bufA
    {
      float accA = bb[160 + l], accB = 0.f;
#pragma unroll
      for (int k = 0; k < 16; k += 4) {
        float4 v = *(const float4*)&bufB[k];
        accA += v.x * wtd1[(k + 0) * 64 + l];
        accB += v.y * wtd1[(k + 1) * 64 + l];
        accA += v.z * wtd1[(k + 2) * 64 + l];
        accB += v.w * wtd1[(k + 3) * 64 + l];
      }
      bufA[l] = prelu(accA + accB, ad1v);
    }
    // d2: bufA -> bufB
    {
      float accA = bb[224 + l], accB = 0.f;
#pragma unroll
      for (int k = 0; k < 64; k += 4) {
        float4 v = *(const float4*)&bufA[k];
        accA += v.x * wtd2[(k + 0) * 64 + l];
        accB += v.y * wtd2[(k + 1) * 64 + l];
        accA += v.z * wtd2[(k + 2) * 64 + l];
        accB += v.w * wtd2[(k + 3) * 64 + l];
      }
      bufB[l] = prelu(accA + accB, ad2v);
    }
    // out = 4*tanh(Wd3 . d2 + bd3): lane l -> outputs 2l, 2l+1
    {
      float acc0 = bb[288 + 2 * l], acc0b = 0.f;
      float acc1 = bb[288 + 2 * l + 1], acc1b = 0.f;
#pragma unroll
      for (int k = 0; k < 64; k += 2) {
        float2 v = *(const float2*)&bufB[k];
        float2 w0 = *(const float2*)&wtd3[(k + 0) * 128 + 2 * l];
        float2 w1 = *(const float2*)&wtd3[(k + 1) * 128 + 2 * l];
        acc0  += v.x * w0.x; acc0b += v.y * w1.x;
        acc1  += v.x * w0.y; acc1b += v.y * w1.y;
      }
      float o0 = 4.0f * tanh_f(acc0 + acc0b);
      float o1 = 4.0f * tanh_f(acc1 + acc1b);
      *(float2*)&out[t * 128 + 2 * l] = make_float2(o0, o1);
    }
  }
}

// =====================================================================
extern "C" void kernel_launch(void* const* d_in, const int* in_sizes, int n_in,
                              void* d_out, int out_size, void* d_ws, size_t ws_size,
                              hipStream_t stream) {
  (void)in_sizes; (void)n_in; (void)out_size;
  const float* x    = (const float*)d_in[0];
  const float* eps  = (const float*)d_in[1];
  const float* h0   = (const float*)d_in[2];
  const float* c0   = (const float*)d_in[3];
  const int*   tr   = (const int*)d_in[4];
  const float* W_ih = (const float*)d_in[5];
  const float* W_hh = (const float*)d_in[6];
  const float* b_ih = (const float*)d_in[7];
  const float* b_hh = (const float*)d_in[8];
  const float* We1  = (const float*)d_in[9];
  const float* be1  = (const float*)d_in[10];
  const float* ae1  = (const float*)d_in[11];
  const float* We2  = (const float*)d_in[12];
  const float* be2  = (const float*)d_in[13];
  const float* ae2  = (const float*)d_in[14];
  const float* We3  = (const float*)d_in[15];
  const float* be3  = (const float*)d_in[16];
  const float* Wd1  = (const float*)d_in[17];
  const float* bd1  = (const float*)d_in[18];
  const float* ad1  = (const float*)d_in[19];
  const float* Wd2  = (const float*)d_in[20];
  const float* bd2  = (const float*)d_in[21];
  const float* ad2  = (const float*)d_in[22];
  const float* Wd3  = (const float*)d_in[23];
  const float* bd3  = (const float*)d_in[24];
  float* out = (float*)d_out;

  // ws layout: [state: 1024B][xg: (ch+8)*1024B]
  char* ws = (char*)d_ws;
  float* state = (float*)ws;
  float* xg    = (float*)(ws + 1024);

  long fit = (ws_size > 2048) ? (long)((ws_size - 1024) / (GATES * sizeof(float))) - 8 : 0;
  long ch = (fit < (long)T_STEPS) ? fit : (long)T_STEPS;
  ch &= ~3L;
  if (ch < 1024) ch = 1024;  // bounds graph at <=129 chunk pairs

  for (long t0 = 0; t0 < T_STEPS; t0 += ch) {
    int n = (int)(((long)T_STEPS - t0 < ch) ? ((long)T_STEPS - t0) : ch);
    hipLaunchKernelGGL(kA, dim3(512), dim3(256), 0, stream,
                       x, W_ih, b_ih, b_hh, xg, (int)t0, n);
    hipLaunchKernelGGL(kB, dim3(1), dim3(64), 0, stream,
                       (const float4*)xg, W_hh, h0, c0, state, out, (int)t0, n,
                       (t0 == 0) ? 1 : 0);
  }
  hipLaunchKernelGGL(kC, dim3(256), dim3(512), 0, stream,
                     eps, tr, We1, be1, ae1, We2, be2, ae2, We3, be3,
                     Wd1, bd1, ad1, Wd2, bd2, ad2, Wd3, bd3, out);
}

// Round 6
// 60860.895 us; speedup vs baseline: 2.1583x; 1.1389x over previous
//
#include <hip/hip_runtime.h>
#include <cstdint>

#define T_STEPS 131072
#define FEATS 128
#define HID 64
#define LAT 16
#define GATES 256  // 4*HID

typedef float v4f __attribute__((ext_vector_type(4)));
typedef _Float16 half_t;
typedef _Float16 half2_t __attribute__((ext_vector_type(2)));
typedef _Float16 v8h __attribute__((ext_vector_type(8)));

#define LOG2E 1.44269504088896340736f

// ---------- math helpers ----------
__device__ __forceinline__ float frcp(float x) { return __builtin_amdgcn_rcpf(x); }
__device__ __forceinline__ float fexp2(float x) { return __builtin_amdgcn_exp2f(x); }

__device__ __forceinline__ float sigm_f(float x) {
  float e = fexp2(-LOG2E * fabsf(x));
  float r = frcp(1.0f + e);
  return x >= 0.0f ? r : e * r;
}
__device__ __forceinline__ float tanh_f(float x) {
  float e = fexp2(-2.0f * LOG2E * fabsf(x));
  float r = (1.0f - e) * frcp(1.0f + e);
  return copysignf(r, x);
}
__device__ __forceinline__ float prelu(float x, float a) { return x > 0.0f ? x : a * x; }

__device__ __forceinline__ float fdot2(half2_t a, half2_t b, float c) {
#if __has_builtin(__builtin_amdgcn_fdot2)
  return __builtin_amdgcn_fdot2(a, b, c, false);
#else
  return c + (float)a.x * (float)b.x + (float)a.y * (float)b.y;
#endif
}

// =====================================================================
// Kernel A: xg4[t][e] = float4(gate i,f,g,o of element e) =
// b[j] + x_t . W_ih[j,:], j = g*64+e.  Layout [t][e][4] so kB's lane e
// reads one coalesced float4 per step.
// =====================================================================
__global__ __launch_bounds__(256) void kA(const float* __restrict__ x,
                                          const float* __restrict__ W_ih,
                                          const float* __restrict__ b_ih,
                                          const float* __restrict__ b_hh,
                                          float* __restrict__ xg,
                                          int t0, int n) {
  __shared__ float wt[FEATS * 128];                 // [k][jj] transposed half
  __shared__ __align__(16) float xb[4][FEATS];      // per-wave x row
  const int tid = threadIdx.x;
  const int w = tid >> 6, l = tid & 63;
  const int half = blockIdx.x & 1;
  const int pair = blockIdx.x >> 1;                 // 0..255

  for (int idx = tid; idx < 128 * FEATS; idx += 256) {
    int jj = idx >> 7, k = idx & 127;
    wt[k * 128 + jj] = W_ih[(size_t)(half * 128 + jj) * FEATS + k];
  }
  const int j0 = half * 128 + 2 * l;                // even row; j0+1 same gate blk
  const float b0 = b_ih[j0] + b_hh[j0];
  const float b1 = b_ih[j0 + 1] + b_hh[j0 + 1];
  const int g0 = j0 >> 6;                           // gate index 0..3
  const int e0 = j0 & 63;                           // element index (even)
  __syncthreads();

  for (int s = pair * 4 + w; s < n; s += 1024) {
    const size_t t = (size_t)(t0 + s);
    *(float2*)&xb[w][2 * l] = *(const float2*)&x[t * FEATS + 2 * l];
    float a0 = b0, a0b = 0.f, a1 = b1, a1b = 0.f;
#pragma unroll
    for (int k = 0; k < FEATS; k += 4) {
      float4 xk = *(const float4*)&xb[w][k];
      float2 w0 = *(const float2*)&wt[(k + 0) * 128 + 2 * l];
      float2 w1 = *(const float2*)&wt[(k + 1) * 128 + 2 * l];
      float2 w2 = *(const float2*)&wt[(k + 2) * 128 + 2 * l];
      float2 w3 = *(const float2*)&wt[(k + 3) * 128 + 2 * l];
      a0  += xk.x * w0.x; a0b += xk.y * w1.x;
      a0  += xk.z * w2.x; a0b += xk.w * w3.x;
      a1  += xk.x * w0.y; a1b += xk.y * w1.y;
      a1  += xk.z * w2.y; a1b += xk.w * w3.y;
    }
    float* dst = &xg[(size_t)s * GATES];
    dst[e0 * 4 + g0]       = a0 + a0b;
    dst[(e0 + 1) * 4 + g0] = a1 + a1b;
  }
}

// =====================================================================
// Kernel B: sequential LSTM recurrence. ONE wave (64 lanes). Lane e owns
// element e; all 4 gate rows of W_hh as 128 INDIVIDUALLY NAMED half2_t
// registers (no arrays/unions -> SROA cannot demote to scratch; round-5's
// VGPR=96 proved array forms spill). v_dot2_f32_f16: 2 MAC/instr.
// h in LDS as packed f16 (128B): 8 uniform ds_read_b128/step, pairs
// extracted with literal-index shufflevector (free sub-reg refs).
// =====================================================================
#define FOR8(M) M(0) M(1) M(2) M(3) M(4) M(5) M(6) M(7)

// declare 16 named half2 weights per q-block (4 per gate)
#define DECLWQ(q)                                                          \
  half2_t wi##q##_0, wi##q##_1, wi##q##_2, wi##q##_3;                      \
  half2_t wf##q##_0, wf##q##_1, wf##q##_2, wf##q##_3;                      \
  half2_t wg##q##_0, wg##q##_1, wg##q##_2, wg##q##_3;                      \
  half2_t wo##q##_0, wo##q##_1, wo##q##_2, wo##q##_3;

#define LOADW1(G, gi, q, r)                                                \
  { float2 t_ = *(const float2*)&W_hh[(size_t)((gi) * HID + e) * HID +     \
                                      8 * (q) + 2 * (r)];                  \
    G##q##_##r = half2_t{(half_t)t_.x, (half_t)t_.y}; }

#define LOADWQ(q)                                                          \
  LOADW1(wi, 0, q, 0) LOADW1(wi, 0, q, 1) LOADW1(wi, 0, q, 2) LOADW1(wi, 0, q, 3) \
  LOADW1(wf, 1, q, 0) LOADW1(wf, 1, q, 1) LOADW1(wf, 1, q, 2) LOADW1(wf, 1, q, 3) \
  LOADW1(wg, 2, q, 0) LOADW1(wg, 2, q, 1) LOADW1(wg, 2, q, 2) LOADW1(wg, 2, q, 3) \
  LOADW1(wo, 3, q, 0) LOADW1(wo, 3, q, 1) LOADW1(wo, 3, q, 2) LOADW1(wo, 3, q, 3)

// one q-block of the matvec: read 8 h values (1 ds_read_b128), 16 fdot2
#define STEP_DOTQ(q)                                                       \
  { v8h hv = ((const v8h*)hbuf)[q];                                        \
    half2_t hA = __builtin_shufflevector(hv, hv, 0, 1);                    \
    half2_t hB = __builtin_shufflevector(hv, hv, 2, 3);                    \
    half2_t hC = __builtin_shufflevector(hv, hv, 4, 5);                    \
    half2_t hD = __builtin_shufflevector(hv, hv, 6, 7);                    \
    ai = fdot2(hA, wi##q##_0, ai); af = fdot2(hA, wf##q##_0, af);          \
    ag = fdot2(hA, wg##q##_0, ag); ao = fdot2(hA, wo##q##_0, ao);          \
    ai = fdot2(hB, wi##q##_1, ai); af = fdot2(hB, wf##q##_1, af);          \
    ag = fdot2(hB, wg##q##_1, ag); ao = fdot2(hB, wo##q##_1, ao);          \
    ai = fdot2(hC, wi##q##_2, ai); af = fdot2(hC, wf##q##_2, af);          \
    ag = fdot2(hC, wg##q##_2, ag); ao = fdot2(hC, wo##q##_2, ao);          \
    ai = fdot2(hD, wi##q##_3, ai); af = fdot2(hD, wf##q##_3, af);          \
    ag = fdot2(hD, wg##q##_3, ag); ao = fdot2(hD, wo##q##_3, ao); }

__global__ __launch_bounds__(64, 1) void kB(const float4* __restrict__ xg4,
                                            const float* __restrict__ W_hh,
                                            const float* __restrict__ h0,
                                            const float* __restrict__ c0,
                                            float* __restrict__ state,
                                            float* __restrict__ h2out,
                                            int t0, int nsteps, int first) {
  __shared__ __align__(16) half_t hbuf[HID];
  const int e = threadIdx.x;                 // 0..63

  FOR8(DECLWQ)
  FOR8(LOADWQ)

  float hinit = first ? h0[e] : state[e];
  hbuf[e] = (half_t)hinit;
  float c_reg = first ? c0[e] : state[HID + e];
  float hlast = hinit;

  float4 x0 = xg4[(size_t)0 * HID + e];
  float4 x1 = xg4[(size_t)1 * HID + e];
  float4 x2 = xg4[(size_t)2 * HID + e];
  float4 x3 = xg4[(size_t)3 * HID + e];

  // pin the weight loads above the loop (loads cannot cross a mem clobber)
  asm volatile("" ::: "memory");

#define LSTM_STEP(XV, S)                                                   \
  {                                                                        \
    float ai = (XV).x, af = (XV).y, ag = (XV).z, ao = (XV).w;              \
    FOR8(STEP_DOTQ)                                                        \
    float tg = tanh_f(ag);                                                 \
    float fv = sigm_f(af);                                                 \
    float iv = sigm_f(ai);                                                 \
    float ov = sigm_f(ao);                                                 \
    float c2 = fv * c_reg + iv * tg;                                       \
    float h2v = ov * tanh_f(c2);                                           \
    c_reg = c2;                                                            \
    hlast = h2v;                                                           \
    hbuf[e] = (half_t)h2v;                                                 \
    h2out[(size_t)(t0 + (S)) * 128 + e] = h2v;                             \
  }

  for (int s = 0; s < nsteps; s += 4) {
    { float4 nx = xg4[(size_t)(s + 4) * HID + e]; LSTM_STEP(x0, s + 0); x0 = nx; }
    { float4 nx = xg4[(size_t)(s + 5) * HID + e]; LSTM_STEP(x1, s + 1); x1 = nx; }
    { float4 nx = xg4[(size_t)(s + 6) * HID + e]; LSTM_STEP(x2, s + 2); x2 = nx; }
    { float4 nx = xg4[(size_t)(s + 7) * HID + e]; LSTM_STEP(x3, s + 3); x3 = nx; }
  }
  state[e] = hlast;
  state[HID + e] = c_reg;
#undef LSTM_STEP
}

// =====================================================================
// Kernel C: VAE encoder/decoder, fully parallel over t. One wave per t,
// 8 waves/block, all weights transposed in LDS (~98KB), ping-pong act bufs.
// h2 arrives in out[t*128+0..63]; row is overwritten by the same wave at
// the end of the iteration.
// =====================================================================
__device__ __forceinline__ void stageT(float* dst, const float* __restrict__ src,
                                       int rows, int colsShift, int tid, int nthr) {
  const int total = rows << colsShift;
  const int cmask = (1 << colsShift) - 1;
  for (int idx = tid; idx < total; idx += nthr) {
    int jr = idx >> colsShift, k = idx & cmask;
    dst[k * rows + jr] = src[idx];
  }
}

__global__ __launch_bounds__(512) void kC(const float* __restrict__ eps,
                                          const int* __restrict__ trainp,
                                          const float* __restrict__ We1, const float* __restrict__ be1, const float* __restrict__ ae1,
                                          const float* __restrict__ We2, const float* __restrict__ be2, const float* __restrict__ ae2,
                                          const float* __restrict__ We3, const float* __restrict__ be3,
                                          const float* __restrict__ Wd1, const float* __restrict__ bd1, const float* __restrict__ ad1,
                                          const float* __restrict__ Wd2, const float* __restrict__ bd2, const float* __restrict__ ad2,
                                          const float* __restrict__ Wd3, const float* __restrict__ bd3,
                                          float* __restrict__ out) {
  __shared__ float wt1[4096], wt2[4096], wt3[2048], wtd1[1024], wtd2[4096], wtd3[8192];
  __shared__ float bb[416];
  __shared__ __align__(16) float abuf[8][2][HID];
  const int tid = threadIdx.x;

  stageT(wt1, We1, 64, 6, tid, 512);
  stageT(wt2, We2, 64, 6, tid, 512);
  stageT(wt3, We3, 32, 6, tid, 512);
  stageT(wtd1, Wd1, 64, 4, tid, 512);
  stageT(wtd2, Wd2, 64, 6, tid, 512);
  stageT(wtd3, Wd3, 128, 6, tid, 512);
  for (int i = tid; i < 416; i += 512) {
    float v;
    if (i < 64)       v = be1[i];
    else if (i < 128) v = be2[i - 64];
    else if (i < 160) v = be3[i - 128];
    else if (i < 224) v = bd1[i - 160];
    else if (i < 288) v = bd2[i - 224];
    else              v = bd3[i - 288];
    bb[i] = v;
  }
  const float a1 = *ae1, a2 = *ae2, ad1v = *ad1, ad2v = *ad2;
  const int train = *trainp;
  __syncthreads();

  const int w = tid >> 6, l = tid & 63, le = l & 15;
  float* bufA = abuf[w][0];
  float* bufB = abuf[w][1];

  for (int it = 0; it < 64; ++it) {
    const size_t t = ((size_t)blockIdx.x << 9) + (size_t)(it << 3) + (size_t)w;
    bufA[l] = out[t * 128 + l];  // h2 row (written by kB)
    // e1 = prelu(We1 . h2 + be1): bufA -> bufB
    {
      float accA = bb[l], accB = 0.f;
#pragma unroll
      for (int k = 0; k < 64; k += 4) {
        float4 v = *(const float4*)&bufA[k];
        accA += v.x * wt1[(k + 0) * 64 + l];
        accB += v.y * wt1[(k + 1) * 64 + l];
        accA += v.z * wt1[(k + 2) * 64 + l];
        accB += v.w * wt1[(k + 3) * 64 + l];
      }
      bufB[l] = prelu(accA + accB, a1);
    }
    // e2: bufB -> bufA
    {
      float accA = bb[64 + l], accB = 0.f;
#pragma unroll
      for (int k = 0; k < 64; k += 4) {
        float4 v = *(const float4*)&bufB[k];
        accA += v.x * wt2[(k + 0) * 64 + l];
        accB += v.y * wt2[(k + 1) * 64 + l];
        accA += v.z * wt2[(k + 2) * 64 + l];
        accB += v.w * wt2[(k + 3) * 64 + l];
      }
      bufA[l] = prelu(accA + accB, a2);
    }
    // ml = We3 . e2 + be3 (32 outputs in lanes 0..31)
    float m;
    {
      const int jj = l & 31;
      float accA = bb[128 + jj], accB = 0.f;
#pragma unroll
      for (int k = 0; k < 64; k += 4) {
        float4 v = *(const float4*)&bufA[k];
        accA += v.x * wt3[(k + 0) * 32 + jj];
        accB += v.y * wt3[(k + 1) * 32 + jj];
        accA += v.z * wt3[(k + 2) * 32 + jj];
        accB += v.w * wt3[(k + 3) * 32 + jj];
      }
      m = accA + accB;
    }
    if (l < 16)      out[(size_t)T_STEPS * 128 + t * LAT + l] = m;          // mu
    else if (l < 32) out[(size_t)T_STEPS * 144 + t * LAT + (l - 16)] = m;   // lv
    float muv = __shfl(m, le);
    float lvv = __shfl(m, 16 + le);
    float ev = eps[t * LAT + le];
    float z = train ? (muv + ev * fexp2(0.5f * LOG2E * lvv)) : muv;
    if (l < 16) bufB[l] = z;
    // d1 = prelu(Wd1 . z + bd1): bufB(16) -> bufA
    {
      float accA = bb[160 + l], accB = 0.f;
#pragma unroll
      for (int k = 0; k < 16; k += 4) {
        float4 v = *(const float4*)&bufB[k];
        accA += v.x * wtd1[(k + 0) * 64 + l];
        accB += v.y * wtd1[(k + 1) * 64 + l];
        accA += v.z * wtd1[(k + 2) * 64 + l];
        accB += v.w * wtd1[(k + 3) * 64 + l];
      }
      bufA[l] = prelu(accA + accB, ad1v);
    }
    // d2: bufA -> bufB
    {
      float accA = bb[224 + l], accB = 0.f;
#pragma unroll
      for (int k = 0; k < 64; k += 4) {
        float4 v = *(const float4*)&bufA[k];
        accA += v.x * wtd2[(k + 0) * 64 + l];
        accB += v.y * wtd2[(k + 1) * 64 + l];
        accA += v.z * wtd2[(k + 2) * 64 + l];
        accB += v.w * wtd2[(k + 3) * 64 + l];
      }
      bufB[l] = prelu(accA + accB, ad2v);
    }
    // out = 4*tanh(Wd3 . d2 + bd3): lane l -> outputs 2l, 2l+1
    {
      float acc0 = bb[288 + 2 * l], acc0b = 0.f;
      float acc1 = bb[288 + 2 * l + 1], acc1b = 0.f;
#pragma unroll
      for (int k = 0; k < 64; k += 2) {
        float2 v = *(const float2*)&bufB[k];
        float2 w0 = *(const float2*)&wtd3[(k + 0) * 128 + 2 * l];
        float2 w1 = *(const float2*)&wtd3[(k + 1) * 128 + 2 * l];
        acc0  += v.x * w0.x; acc0b += v.y * w1.x;
        acc1  += v.x * w0.y; acc1b += v.y * w1.y;
      }
      float o0 = 4.0f * tanh_f(acc0 + acc0b);
      float o1 = 4.0f * tanh_f(acc1 + acc1b);
      *(float2*)&out[t * 128 + 2 * l] = make_float2(o0, o1);
    }
  }
}

// =====================================================================
extern "C" void kernel_launch(void* const* d_in, const int* in_sizes, int n_in,
                              void* d_out, int out_size, void* d_ws, size_t ws_size,
                              hipStream_t stream) {
  (void)in_sizes; (void)n_in; (void)out_size;
  const float* x    = (const float*)d_in[0];
  const float* eps  = (const float*)d_in[1];
  const float* h0   = (const float*)d_in[2];
  const float* c0   = (const float*)d_in[3];
  const int*   tr   = (const int*)d_in[4];
  const float* W_ih = (const float*)d_in[5];
  const float* W_hh = (const float*)d_in[6];
  const float* b_ih = (const float*)d_in[7];
  const float* b_hh = (const float*)d_in[8];
  const float* We1  = (const float*)d_in[9];
  const float* be1  = (const float*)d_in[10];
  const float* ae1  = (const float*)d_in[11];
  const float* We2  = (const float*)d_in[12];
  const float* be2  = (const float*)d_in[13];
  const float* ae2  = (const float*)d_in[14];
  const float* We3  = (const float*)d_in[15];
  const float* be3  = (const float*)d_in[16];
  const float* Wd1  = (const float*)d_in[17];
  const float* bd1  = (const float*)d_in[18];
  const float* ad1  = (const float*)d_in[19];
  const float* Wd2  = (const float*)d_in[20];
  const float* bd2  = (const float*)d_in[21];
  const float* ad2  = (const float*)d_in[22];
  const float* Wd3  = (const float*)d_in[23];
  const float* bd3  = (const float*)d_in[24];
  float* out = (float*)d_out;

  // ws layout: [state: 1024B][xg: (ch+8)*1024B]
  char* ws = (char*)d_ws;
  float* state = (float*)ws;
  float* xg    = (float*)(ws + 1024);

  long fit = (ws_size > 2048) ? (long)((ws_size - 1024) / (GATES * sizeof(float))) - 8 : 0;
  long ch = (fit < (long)T_STEPS) ? fit : (long)T_STEPS;
  ch &= ~3L;
  if (ch < 1024) ch = 1024;  // bounds graph at <=129 chunk pairs

  for (long t0 = 0; t0 < T_STEPS; t0 += ch) {
    int n = (int)(((long)T_STEPS - t0 < ch) ? ((long)T_STEPS - t0) : ch);
    hipLaunchKernelGGL(kA, dim3(512), dim3(256), 0, stream,
                       x, W_ih, b_ih, b_hh, xg, (int)t0, n);
    hipLaunchKernelGGL(kB, dim3(1), dim3(64), 0, stream,
                       (const float4*)xg, W_hh, h0, c0, state, out, (int)t0, n,
                       (t0 == 0) ? 1 : 0);
  }
  hipLaunchKernelGGL(kC, dim3(256), dim3(512), 0, stream,
                     eps, tr, We1, be1, ae1, We2, be2, ae2, We3, be3,
                     Wd1, bd1, ad1, Wd2, bd2, ad2, Wd3, bd3, out);
}